// Round 1
// baseline (698.920 us; speedup 1.0000x reference)
//
#include <hip/hip_runtime.h>
#include <cstdint>
#include <cstddef>

typedef unsigned short u16;
typedef short bf16x8 __attribute__((ext_vector_type(8)));
typedef float f32x4 __attribute__((ext_vector_type(4)));

static constexpr int Bb = 4, Tt = 2048, Dd = 1024, NFf = 512, NBb = 4;
static constexpr int Mm = Bb * Tt;      // 8192 tokens
static constexpr int NZz = 4736;        // packed projection width (4613 padded to 37*128)
static constexpr int Ll = 64;           // conv kernel support (0.5^64 ~ 5e-20, negligible)

#define DEV __device__ __forceinline__

DEV u16 f2bf(float f) {
    uint32_t u = __float_as_uint(f);
    u = (u + 0x7FFF + ((u >> 16) & 1)) >> 16;   // RNE
    return (u16)u;
}
DEV float bf2f(u16 h) { return __uint_as_float(((uint32_t)h) << 16); }
DEV float sigm(float x) { return 1.0f / (1.0f + __expf(-x)); }

// ---------------------------------------------------------------- weight prep
__global__ __launch_bounds__(256) void wpack_kernel(
    const float* __restrict__ Wconcept, const float* __restrict__ Wcg,
    const float* __restrict__ Wfg, const float* __restrict__ Wgate,
    const float* __restrict__ Wsp, const float* __restrict__ Wtg,
    const float* __restrict__ Wband,
    const float* __restrict__ bconcept, const float* __restrict__ bcg,
    const float* __restrict__ bfg, const float* __restrict__ bgate,
    const float* __restrict__ btg, const float* __restrict__ bband,
    u16* __restrict__ wcat, float* __restrict__ bias_cat)
{
    int i = blockIdx.x * 256 + threadIdx.x;
    if (i >= NZz * Dd) return;
    int r = i >> 10, c = i & 1023;
    float v;
    if      (r < 1024) v = Wconcept[r * 1024 + c];
    else if (r < 2048) v = Wcg[(r - 1024) * 1024 + c];
    else if (r < 2560) v = Wfg[(r - 2048) * 1024 + c];
    else if (r < 3584) v = Wgate[(r - 2560) * 1024 + c];
    else if (r < 4608) v = Wsp[(r - 3584) * 1024 + c];
    else if (r == 4608) v = Wtg[c];
    else if (r < 4613) v = Wband[(r - 4609) * 1024 + c];
    else v = 0.0f;
    wcat[i] = f2bf(v);
    if (c == 0) {
        float bv;
        if      (r < 1024) bv = bconcept[r];
        else if (r < 2048) bv = bcg[r - 1024];
        else if (r < 2560) bv = bfg[r - 2048];
        else if (r < 3584) bv = bgate[r - 2560];
        else if (r < 4608) bv = 0.0f;                 // Wsp: no bias
        else if (r == 4608) bv = btg[0];
        else if (r < 4613) bv = bband[r - 4609];
        else bv = 0.0f;
        bias_cat[r] = bv;
    }
}

__global__ __launch_bounds__(256) void f2bf_kernel(const float* __restrict__ src,
                                                   u16* __restrict__ dst, int n)
{
    int i = blockIdx.x * 256 + threadIdx.x;
    if (i < n) dst[i] = f2bf(src[i]);
}

// ---------------------------------------------------------------- LayerNorm 1
__global__ __launch_bounds__(256) void ln_kernel(
    const float* __restrict__ x, const float* __restrict__ g,
    const float* __restrict__ b, u16* __restrict__ out_bf)
{
    const int m = blockIdx.x, tid = threadIdx.x;
    float4 v = ((const float4*)(x + (size_t)m * Dd))[tid];
    float s1 = v.x + v.y + v.z + v.w;
    float s2 = v.x * v.x + v.y * v.y + v.z * v.z + v.w * v.w;
    __shared__ float lds[16];
    for (int o = 32; o; o >>= 1) { s1 += __shfl_down(s1, o); s2 += __shfl_down(s2, o); }
    int lane = tid & 63, w = tid >> 6;
    if (!lane) { lds[w] = s1; lds[8 + w] = s2; }
    __syncthreads();
    s1 = lds[0] + lds[1] + lds[2] + lds[3];
    s2 = lds[8] + lds[9] + lds[10] + lds[11];
    float mean = s1 * (1.0f / Dd);
    float var  = s2 * (1.0f / Dd) - mean * mean;
    float rstd = rsqrtf(var + 1e-5f);
    float4 gv = ((const float4*)g)[tid];
    float4 bv = ((const float4*)b)[tid];
    ushort4 o;
    o.x = f2bf((v.x - mean) * rstd * gv.x + bv.x);
    o.y = f2bf((v.y - mean) * rstd * gv.y + bv.y);
    o.z = f2bf((v.z - mean) * rstd * gv.z + bv.z);
    o.w = f2bf((v.w - mean) * rstd * gv.w + bv.w);
    ((ushort4*)(out_bf + (size_t)m * Dd))[tid] = o;
}

// ---------------------------------------------------------------- GEMM (bf16 MFMA)
// C[m,n] = sum_k A[m,k] * Bw[n,k]   A: MxK bf16, Bw: NxK bf16 (weight layout)
// MODE 0: bf16 out = acc + bias[n]
// MODE 1: f32 out = acc
// MODE 2: bf16 out = gelu_exact(acc + bias[n])
// MODE 3: f32 out = acc + bias[n] + add[m,n]
template<int MODE>
__global__ __launch_bounds__(256, 2) void gemm_bt(
    const u16* __restrict__ A, const u16* __restrict__ Bw,
    const float* __restrict__ bias, const float* __restrict__ add,
    void* __restrict__ Cout, int M, int N, int K)
{
    __shared__ __align__(16) u16 smA[128 * 32];
    __shared__ __align__(16) u16 smB[128 * 32];
    const int tid = threadIdx.x;
    const int m0 = blockIdx.x * 128;
    const int n0 = blockIdx.y * 128;
    const int w = tid >> 6, lane = tid & 63;
    const int wr = w >> 1, wc = w & 1;
    const int quad = lane >> 4, l16 = lane & 15;

    const int r0 = tid >> 2, c0 = tid & 3;
    const int r1 = (tid + 256) >> 2, c1 = c0;   // (tid+256)&3 == tid&3

    const u16* gA0 = A + (size_t)(m0 + r0) * K + c0 * 8;
    const u16* gA1 = A + (size_t)(m0 + r1) * K + c1 * 8;
    const u16* gB0 = Bw + (size_t)(n0 + r0) * K + c0 * 8;
    const u16* gB1 = Bw + (size_t)(n0 + r1) * K + c1 * 8;

    f32x4 acc[4][4];
#pragma unroll
    for (int i = 0; i < 4; i++)
#pragma unroll
        for (int j = 0; j < 4; j++) acc[i][j] = {0.f, 0.f, 0.f, 0.f};

    for (int k0 = 0; k0 < K; k0 += 32) {
        uint4 va0 = *(const uint4*)(gA0 + k0);
        uint4 va1 = *(const uint4*)(gA1 + k0);
        uint4 vb0 = *(const uint4*)(gB0 + k0);
        uint4 vb1 = *(const uint4*)(gB1 + k0);
        __syncthreads();
        *(uint4*)&smA[r0 * 32 + c0 * 8] = va0;
        *(uint4*)&smA[r1 * 32 + c1 * 8] = va1;
        *(uint4*)&smB[r0 * 32 + c0 * 8] = vb0;
        *(uint4*)&smB[r1 * 32 + c1 * 8] = vb1;
        __syncthreads();
        bf16x8 af[4], bfv[4];
#pragma unroll
        for (int mi = 0; mi < 4; mi++)
            af[mi] = *(const bf16x8*)&smA[(wr * 64 + mi * 16 + l16) * 32 + quad * 8];
#pragma unroll
        for (int ni = 0; ni < 4; ni++)
            bfv[ni] = *(const bf16x8*)&smB[(wc * 64 + ni * 16 + l16) * 32 + quad * 8];
#pragma unroll
        for (int mi = 0; mi < 4; mi++)
#pragma unroll
            for (int ni = 0; ni < 4; ni++)
                acc[mi][ni] = __builtin_amdgcn_mfma_f32_16x16x32_bf16(
                    af[mi], bfv[ni], acc[mi][ni], 0, 0, 0);
    }

#pragma unroll
    for (int mi = 0; mi < 4; mi++) {
#pragma unroll
        for (int ni = 0; ni < 4; ni++) {
            const int gn = n0 + wc * 64 + ni * 16 + l16;
            const int gmb = m0 + wr * 64 + mi * 16 + quad * 4;
#pragma unroll
            for (int r = 0; r < 4; r++) {
                const int gm = gmb + r;
                float v = acc[mi][ni][r];
                if constexpr (MODE == 0) {
                    ((u16*)Cout)[(size_t)gm * N + gn] = f2bf(v + bias[gn]);
                } else if constexpr (MODE == 1) {
                    ((float*)Cout)[(size_t)gm * N + gn] = v;
                } else if constexpr (MODE == 2) {
                    float t = v + bias[gn];
                    float ge = 0.5f * t * (1.0f + erff(t * 0.70710678118f));
                    ((u16*)Cout)[(size_t)gm * N + gn] = f2bf(ge);
                } else {
                    ((float*)Cout)[(size_t)gm * N + gn] = v + bias[gn] + add[(size_t)gm * N + gn];
                }
            }
        }
    }
}

// ---------------------------------------------------------------- spectral prep
__global__ __launch_bounds__(512) void prep_freq_kernel(
    const float* __restrict__ fi, const float* __restrict__ logd,
    const float* __restrict__ freqs, const float* __restrict__ dt,
    float* __restrict__ rr, float* __restrict__ ri,
    float* __restrict__ Ar, float* __restrict__ Ai)
{
    __shared__ float red[512];
    int f = threadIdx.x;
    float v = fi[f];
    red[f] = v; __syncthreads();
    for (int s = 256; s > 0; s >>= 1) { if (f < s) red[f] = fmaxf(red[f], red[f + s]); __syncthreads(); }
    float mx = red[0]; __syncthreads();
    float e = expf(v - mx);
    red[f] = e; __syncthreads();
    for (int s = 256; s > 0; s >>= 1) { if (f < s) red[f] += red[f + s]; __syncthreads(); }
    float sm = e / red[0];
    float decay = sigm(logd[f]) * (sm * (float)NFf);
    float omega = freqs[f] * 0.1f * (sigm(dt[f]) * 2.0f);
    float cc = cosf(omega), ss = sinf(omega);
    rr[f] = cc; ri[f] = ss; Ar[f] = decay * cc; Ai[f] = decay * ss;
}

// u = (sp_re + i sp_im) * sigmoid(fg); also extract ts, bs
__global__ __launch_bounds__(256) void prepA_kernel(
    const u16* __restrict__ Z, float* __restrict__ u_re, float* __restrict__ u_im,
    float* __restrict__ ts, float* __restrict__ bs)
{
    int i = blockIdx.x * 256 + threadIdx.x;
    if (i >= Mm * NFf) return;
    int m = i >> 9, f = i & (NFf - 1);
    const u16* zr = Z + (size_t)m * NZz;
    float fg  = sigm(bf2f(zr[2048 + f]));
    float spr = bf2f(zr[3584 + f]);
    float spi = bf2f(zr[3584 + NFf + f]);
    u_re[i] = spr * fg;
    u_im[i] = spi * fg;
    if (f == 0) {
        ts[m] = sigm(bf2f(zr[4608]));
#pragma unroll
        for (int j = 0; j < NBb; j++) bs[m * NBb + j] = sigm(bf2f(zr[4609 + j]));
    }
}

// k[b,tau,f] = ts[b,tau] * rot[f] * prod_{s<tau} (A[f]*bs[b,s,band(f)])
__global__ __launch_bounds__(256) void makek_kernel(
    const float* __restrict__ Ar, const float* __restrict__ Ai,
    const float* __restrict__ rr, const float* __restrict__ ri,
    const float* __restrict__ ts, const float* __restrict__ bs,
    float* __restrict__ k_re, float* __restrict__ k_im)
{
    int g = blockIdx.x * 256 + threadIdx.x;
    if (g >= Bb * NFf) return;
    int b = g / NFf, f = g % NFf;
    float Pr = 1.0f, Pi = 0.0f;
    float ar = Ar[f], ai = Ai[f], cr = rr[f], ci = ri[f];
    int band = f / (NFf / NBb);
    for (int tau = 0; tau < Ll; tau++) {
        float tsv = ts[b * Tt + tau];
        k_re[(size_t)(b * Ll + tau) * NFf + f] = tsv * (cr * Pr - ci * Pi);
        k_im[(size_t)(b * Ll + tau) * NFf + f] = tsv * (cr * Pi + ci * Pr);
        float bsv = bs[(b * Tt + tau) * NBb + band];
        float er = ar * bsv, ei = ai * bsv;
        float nPr = Pr * er - Pi * ei;
        float nPi = Pr * ei + Pi * er;
        Pr = nPr; Pi = nPi;
    }
}

// y[b,t,f] = sum_{tau<=min(t,L-1)} u[b,t-tau,f] * k[b,tau,f]; write bf16 spectral_out
__global__ __launch_bounds__(256) void conv_kernel(
    const float* __restrict__ u_re, const float* __restrict__ u_im,
    const float* __restrict__ k_re, const float* __restrict__ k_im,
    u16* __restrict__ spec)
{
    int f = blockIdx.x * 64 + threadIdx.x;
    int t = blockIdx.y * 4 + threadIdx.y;
    int b = blockIdx.z;
    size_t base_u = (size_t)(b * Tt + t) * NFf + f;
    size_t base_k = (size_t)(b * Ll) * NFf + f;
    float yr = 0.0f, yi = 0.0f;
    int tmax = min(Ll, t + 1);
    for (int tau = 0; tau < tmax; tau++) {
        float ur = u_re[base_u - (size_t)tau * NFf];
        float ui = u_im[base_u - (size_t)tau * NFf];
        float kr = k_re[base_k + (size_t)tau * NFf];
        float ki = k_im[base_k + (size_t)tau * NFf];
        yr += ur * kr - ui * ki;
        yi += ur * ki + ui * kr;
    }
    size_t row = (size_t)(b * Tt + t);
    spec[row * (2 * NFf) + f]       = f2bf(yr);
    spec[row * (2 * NFf) + NFf + f] = f2bf(yi);
}

// x2 = x + 0.5*(P2*os*sigmoid(gate) + concept*sigmoid(cg)); xn2 = LN2(x2) bf16
__global__ __launch_bounds__(256) void fuse2_ln_kernel(
    const float* __restrict__ x, const u16* __restrict__ Z,
    const float* __restrict__ P2, const float* __restrict__ osc,
    const float* __restrict__ g2, const float* __restrict__ b2v,
    float* __restrict__ x2, u16* __restrict__ xn2)
{
    const int m = blockIdx.x, tid = threadIdx.x;
    const float os = osc[0];
    const u16* zr = Z + (size_t)m * NZz;
    float4 xv = ((const float4*)(x + (size_t)m * Dd))[tid];
    float4 pv = ((const float4*)(P2 + (size_t)m * Dd))[tid];
    float vals[4]; float s1 = 0.0f, s2 = 0.0f;
#pragma unroll
    for (int j = 0; j < 4; j++) {
        int d = tid * 4 + j;
        float concept = bf2f(zr[d]);
        float cg   = sigm(bf2f(zr[1024 + d]));
        float gate = sigm(bf2f(zr[2560 + d]));
        float p = (&pv.x)[j];
        float v = (&xv.x)[j] + 0.5f * (p * os * gate + concept * cg);
        vals[j] = v; s1 += v; s2 += v * v;
    }
    __shared__ float lds[16];
    for (int o = 32; o; o >>= 1) { s1 += __shfl_down(s1, o); s2 += __shfl_down(s2, o); }
    int lane = tid & 63, w = tid >> 6;
    if (!lane) { lds[w] = s1; lds[8 + w] = s2; }
    __syncthreads();
    s1 = lds[0] + lds[1] + lds[2] + lds[3];
    s2 = lds[8] + lds[9] + lds[10] + lds[11];
    float mean = s1 * (1.0f / Dd);
    float var  = s2 * (1.0f / Dd) - mean * mean;
    float rstd = rsqrtf(var + 1e-5f);
    float4 xo; ushort4 no;
#pragma unroll
    for (int j = 0; j < 4; j++) {
        int d = tid * 4 + j;
        (&xo.x)[j] = vals[j];
        (&no.x)[j] = f2bf((vals[j] - mean) * rstd * g2[d] + b2v[d]);
    }
    ((float4*)(x2 + (size_t)m * Dd))[tid] = xo;
    ((ushort4*)(xn2 + (size_t)m * Dd))[tid] = no;
}

// ---------------------------------------------------------------- launch
extern "C" void kernel_launch(void* const* d_in, const int* in_sizes, int n_in,
                              void* d_out, int out_size, void* d_ws, size_t ws_size,
                              hipStream_t stream)
{
    const float* x        = (const float*)d_in[0];
    const float* norm_g   = (const float*)d_in[1];
    const float* norm_b   = (const float*)d_in[2];
    const float* Wconcept = (const float*)d_in[3];
    const float* bconcept = (const float*)d_in[4];
    const float* Wcg      = (const float*)d_in[5];
    const float* bcg      = (const float*)d_in[6];
    const float* Wfg      = (const float*)d_in[7];
    const float* bfg      = (const float*)d_in[8];
    const float* Wtg      = (const float*)d_in[9];
    const float* btg      = (const float*)d_in[10];
    const float* Wband    = (const float*)d_in[11];
    const float* bband    = (const float*)d_in[12];
    const float* Wsp      = (const float*)d_in[13];
    const float* fi       = (const float*)d_in[14];
    const float* logd     = (const float*)d_in[15];
    const float* freqs    = (const float*)d_in[16];
    const float* dtv      = (const float*)d_in[17];
    const float* Wgate    = (const float*)d_in[18];
    const float* bgate    = (const float*)d_in[19];
    const float* Wfs      = (const float*)d_in[20];
    const float* osc      = (const float*)d_in[21];
    const float* n2g      = (const float*)d_in[22];
    const float* n2b      = (const float*)d_in[23];
    const float* W1       = (const float*)d_in[24];
    const float* b1       = (const float*)d_in[25];
    const float* W2       = (const float*)d_in[26];
    const float* b2       = (const float*)d_in[27];

    char* ws = (char*)d_ws;
    size_t off = 0;
    auto alloc = [&](size_t bytes) { size_t c = off; off += (bytes + 255) & ~(size_t)255; return c; };
    size_t o_wcat = alloc((size_t)NZz * Dd * 2);
    size_t o_bias = alloc((size_t)NZz * 4);
    size_t o_wfs  = alloc((size_t)Dd * 2 * NFf * 2);
    size_t o_w1   = alloc((size_t)4 * Dd * Dd * 2);
    size_t o_w2   = alloc((size_t)4 * Dd * Dd * 2);
    size_t o_xn   = alloc((size_t)Mm * Dd * 2);
    size_t o_Z    = alloc((size_t)Mm * NZz * 2);        // later reused for h (Mm*4096*2 fits)
    size_t o_u    = alloc((size_t)Mm * NFf * 4 * 2);    // u_re|u_im; later P2, then x2 (in place)
    size_t o_spec = alloc((size_t)Mm * Dd * 2);         // spectral; later xn2
    size_t o_kre  = alloc((size_t)Bb * Ll * NFf * 4);
    size_t o_kim  = alloc((size_t)Bb * Ll * NFf * 4);
    size_t o_rr   = alloc(NFf * 4);
    size_t o_ri   = alloc(NFf * 4);
    size_t o_Ar   = alloc(NFf * 4);
    size_t o_Ai   = alloc(NFf * 4);
    size_t o_ts   = alloc(Mm * 4);
    size_t o_bs   = alloc((size_t)Mm * NBb * 4);
    if (ws_size < off) return;   // workspace too small -> visible as validation failure

    u16*   wcat = (u16*)(ws + o_wcat);
    float* bias = (float*)(ws + o_bias);
    u16*   wfs  = (u16*)(ws + o_wfs);
    u16*   w1b  = (u16*)(ws + o_w1);
    u16*   w2b  = (u16*)(ws + o_w2);
    u16*   xn   = (u16*)(ws + o_xn);
    u16*   Zb   = (u16*)(ws + o_Z);
    u16*   hb   = (u16*)(ws + o_Z);
    float* u_re = (float*)(ws + o_u);
    float* u_im = (float*)(ws + o_u + (size_t)Mm * NFf * 4);
    float* P2   = (float*)(ws + o_u);
    float* x2   = (float*)(ws + o_u);     // in-place over P2 (same-thread read->write)
    u16*   spec = (u16*)(ws + o_spec);
    u16*   xn2  = (u16*)(ws + o_spec);
    float* kre  = (float*)(ws + o_kre);
    float* kim  = (float*)(ws + o_kim);
    float* rr   = (float*)(ws + o_rr);
    float* ri   = (float*)(ws + o_ri);
    float* Ar   = (float*)(ws + o_Ar);
    float* Ai   = (float*)(ws + o_Ai);
    float* ts   = (float*)(ws + o_ts);
    float* bs   = (float*)(ws + o_bs);

    // 1) weight packing / bf16 conversion
    wpack_kernel<<<(NZz * Dd + 255) / 256, 256, 0, stream>>>(
        Wconcept, Wcg, Wfg, Wgate, Wsp, Wtg, Wband,
        bconcept, bcg, bfg, bgate, btg, bband, wcat, bias);
    f2bf_kernel<<<(Dd * 2 * NFf + 255) / 256, 256, 0, stream>>>(Wfs, wfs, Dd * 2 * NFf);
    f2bf_kernel<<<(4 * Dd * Dd + 255) / 256, 256, 0, stream>>>(W1, w1b, 4 * Dd * Dd);
    f2bf_kernel<<<(4 * Dd * Dd + 255) / 256, 256, 0, stream>>>(W2, w2b, 4 * Dd * Dd);

    // 2) LN1 -> xn (bf16)
    ln_kernel<<<Mm, 256, 0, stream>>>(x, norm_g, norm_b, xn);

    // 3) fused projection GEMM: Z = xn @ wcat^T + bias  (8192 x 4736, K=1024)
    gemm_bt<0><<<dim3(Mm / 128, NZz / 128), 256, 0, stream>>>(
        xn, wcat, bias, nullptr, (void*)Zb, Mm, NZz, Dd);

    // 4) spectral constants, u, conv kernel coefficients
    prep_freq_kernel<<<1, 512, 0, stream>>>(fi, logd, freqs, dtv, rr, ri, Ar, Ai);
    prepA_kernel<<<(Mm * NFf + 255) / 256, 256, 0, stream>>>(Zb, u_re, u_im, ts, bs);
    makek_kernel<<<(Bb * NFf + 255) / 256, 256, 0, stream>>>(Ar, Ai, rr, ri, ts, bs, kre, kim);

    // 5) truncated causal convolution -> spectral_out (bf16)
    conv_kernel<<<dim3(NFf / 64, Tt / 4, Bb), dim3(64, 4), 0, stream>>>(u_re, u_im, kre, kim, spec);

    // 6) y_proj raw: P2 = spectral @ Wfs^T   (8192 x 1024, K=2048)
    gemm_bt<1><<<dim3(Mm / 128, Dd / 128), 256, 0, stream>>>(
        spec, wfs, nullptr, nullptr, (void*)P2, Mm, Dd, 2 * NFf);

    // 7) gate/concept fuse + residual + LN2
    fuse2_ln_kernel<<<Mm, 256, 0, stream>>>(x, Zb, P2, osc, n2g, n2b, x2, xn2);

    // 8) MLP
    gemm_bt<2><<<dim3(Mm / 128, (4 * Dd) / 128), 256, 0, stream>>>(
        xn2, w1b, b1, nullptr, (void*)hb, Mm, 4 * Dd, Dd);
    gemm_bt<3><<<dim3(Mm / 128, Dd / 128), 256, 0, stream>>>(
        hb, w2b, b2, x2, d_out, Mm, Dd, 4 * Dd);
}

// Round 2
// 639.031 us; speedup vs baseline: 1.0937x; 1.0937x over previous
//
#include <hip/hip_runtime.h>
#include <cstdint>
#include <cstddef>

typedef unsigned short u16;
typedef unsigned int u32;
typedef short bf16x8 __attribute__((ext_vector_type(8)));
typedef float f32x4 __attribute__((ext_vector_type(4)));

static constexpr int Bb = 4, Tt = 2048, Dd = 1024, NFf = 512, NBb = 4;
static constexpr int Mm = Bb * Tt;      // 8192 tokens
static constexpr int NZz = 4736;        // packed projection width (4613 padded to 37*128)
static constexpr int Ll = 64;           // conv kernel support (0.5^64 ~ 5e-20, negligible)

#define DEV __device__ __forceinline__

typedef const __attribute__((address_space(1))) u32* gas_p;
typedef __attribute__((address_space(3))) u32* las_p;

DEV u16 f2bf(float f) {
    uint32_t u = __float_as_uint(f);
    u = (u + 0x7FFF + ((u >> 16) & 1)) >> 16;   // RNE
    return (u16)u;
}
DEV float bf2f(u16 h) { return __uint_as_float(((uint32_t)h) << 16); }
DEV float sigm(float x) { return 1.0f / (1.0f + __expf(-x)); }

// ---------------------------------------------------------------- weight prep
__global__ __launch_bounds__(256) void wpack_kernel(
    const float* __restrict__ Wconcept, const float* __restrict__ Wcg,
    const float* __restrict__ Wfg, const float* __restrict__ Wgate,
    const float* __restrict__ Wsp, const float* __restrict__ Wtg,
    const float* __restrict__ Wband,
    const float* __restrict__ bconcept, const float* __restrict__ bcg,
    const float* __restrict__ bfg, const float* __restrict__ bgate,
    const float* __restrict__ btg, const float* __restrict__ bband,
    u16* __restrict__ wcat, float* __restrict__ bias_cat)
{
    int i = blockIdx.x * 256 + threadIdx.x;
    if (i >= NZz * Dd) return;
    int r = i >> 10, c = i & 1023;
    float v;
    if      (r < 1024) v = Wconcept[r * 1024 + c];
    else if (r < 2048) v = Wcg[(r - 1024) * 1024 + c];
    else if (r < 2560) v = Wfg[(r - 2048) * 1024 + c];
    else if (r < 3584) v = Wgate[(r - 2560) * 1024 + c];
    else if (r < 4608) v = Wsp[(r - 3584) * 1024 + c];
    else if (r == 4608) v = Wtg[c];
    else if (r < 4613) v = Wband[(r - 4609) * 1024 + c];
    else v = 0.0f;
    wcat[i] = f2bf(v);
    if (c == 0) {
        float bv;
        if      (r < 1024) bv = bconcept[r];
        else if (r < 2048) bv = bcg[r - 1024];
        else if (r < 2560) bv = bfg[r - 2048];
        else if (r < 3584) bv = bgate[r - 2560];
        else if (r < 4608) bv = 0.0f;                 // Wsp: no bias
        else if (r == 4608) bv = btg[0];
        else if (r < 4613) bv = bband[r - 4609];
        else bv = 0.0f;
        bias_cat[r] = bv;
    }
}

__global__ __launch_bounds__(256) void f2bf_kernel(const float* __restrict__ src,
                                                   u16* __restrict__ dst, int n)
{
    int i = blockIdx.x * 256 + threadIdx.x;
    if (i < n) dst[i] = f2bf(src[i]);
}

// ---------------------------------------------------------------- LayerNorm 1
__global__ __launch_bounds__(256) void ln_kernel(
    const float* __restrict__ x, const float* __restrict__ g,
    const float* __restrict__ b, u16* __restrict__ out_bf)
{
    const int m = blockIdx.x, tid = threadIdx.x;
    float4 v = ((const float4*)(x + (size_t)m * Dd))[tid];
    float s1 = v.x + v.y + v.z + v.w;
    float s2 = v.x * v.x + v.y * v.y + v.z * v.z + v.w * v.w;
    __shared__ float lds[16];
    for (int o = 32; o; o >>= 1) { s1 += __shfl_down(s1, o); s2 += __shfl_down(s2, o); }
    int lane = tid & 63, w = tid >> 6;
    if (!lane) { lds[w] = s1; lds[8 + w] = s2; }
    __syncthreads();
    s1 = lds[0] + lds[1] + lds[2] + lds[3];
    s2 = lds[8] + lds[9] + lds[10] + lds[11];
    float mean = s1 * (1.0f / Dd);
    float var  = s2 * (1.0f / Dd) - mean * mean;
    float rstd = rsqrtf(var + 1e-5f);
    float4 gv = ((const float4*)g)[tid];
    float4 bv = ((const float4*)b)[tid];
    ushort4 o;
    o.x = f2bf((v.x - mean) * rstd * gv.x + bv.x);
    o.y = f2bf((v.y - mean) * rstd * gv.y + bv.y);
    o.z = f2bf((v.z - mean) * rstd * gv.z + bv.z);
    o.w = f2bf((v.w - mean) * rstd * gv.w + bv.w);
    ((ushort4*)(out_bf + (size_t)m * Dd))[tid] = o;
}

// ---------------------------------------------------------------- GEMM (bf16 MFMA)
// C[m,n] = sum_k A[m,k] * Bw[n,k]   A: MxK bf16, Bw: NxK bf16 (weight layout)
// Staging via global_load_lds width=16 (m97 structure).
// MODE 0: bf16 out = acc + bias[n]
// MODE 1: f32 out = acc
// MODE 2: bf16 out = gelu_exact(acc + bias[n])
// MODE 3: f32 out = acc + bias[n] + add[m,n]
template<int MODE>
__global__ __launch_bounds__(256, 2) void gemm_bt(
    const u16* __restrict__ A, const u16* __restrict__ Bw,
    const float* __restrict__ bias, const float* __restrict__ add,
    void* __restrict__ Cout, int M, int N, int K)
{
    __shared__ __align__(16) u16 smA[128 * 32];
    __shared__ __align__(16) u16 smB[128 * 32];
    const int tid = threadIdx.x;
    const int m0 = blockIdx.x * 128;
    const int n0 = blockIdx.y * 128;
    const int w = tid >> 6, lane = tid & 63;
    const int wr = w >> 1, wc = w & 1;
    const int quad = lane >> 4, l16 = lane & 15;

    // staging: thread t owns 16B chunk t -> row t/4, k-chunk (t&3)*8
    const int r0 = tid >> 2, c0 = tid & 3;
    const u16* gA0 = A + (size_t)(m0 + r0) * K + c0 * 8;
    const u16* gA1 = gA0 + (size_t)64 * K;
    const u16* gB0 = Bw + (size_t)(n0 + r0) * K + c0 * 8;
    const u16* gB1 = gB0 + (size_t)64 * K;
    // LDS dest (contiguous in lane order; HW uses wave base + lane*16)
    las_p lA0 = (las_p)(smA + tid * 8);
    las_p lA1 = (las_p)(smA + 2048 + tid * 8);
    las_p lB0 = (las_p)(smB + tid * 8);
    las_p lB1 = (las_p)(smB + 2048 + tid * 8);

    f32x4 acc[4][4];
#pragma unroll
    for (int i = 0; i < 4; i++)
#pragma unroll
        for (int j = 0; j < 4; j++) acc[i][j] = {0.f, 0.f, 0.f, 0.f};

    for (int k0 = 0; k0 < K; k0 += 32) {
        __syncthreads();   // previous tile's compute done
        __builtin_amdgcn_global_load_lds((gas_p)(gA0 + k0), lA0, 16, 0, 0);
        __builtin_amdgcn_global_load_lds((gas_p)(gA1 + k0), lA1, 16, 0, 0);
        __builtin_amdgcn_global_load_lds((gas_p)(gB0 + k0), lB0, 16, 0, 0);
        __builtin_amdgcn_global_load_lds((gas_p)(gB1 + k0), lB1, 16, 0, 0);
        __syncthreads();   // drains vmcnt(0) + barrier -> LDS tile visible
        bf16x8 af[4], bfv[4];
#pragma unroll
        for (int mi = 0; mi < 4; mi++)
            af[mi] = *(const bf16x8*)&smA[(wr * 64 + mi * 16 + l16) * 32 + quad * 8];
#pragma unroll
        for (int ni = 0; ni < 4; ni++)
            bfv[ni] = *(const bf16x8*)&smB[(wc * 64 + ni * 16 + l16) * 32 + quad * 8];
#pragma unroll
        for (int mi = 0; mi < 4; mi++)
#pragma unroll
            for (int ni = 0; ni < 4; ni++)
                acc[mi][ni] = __builtin_amdgcn_mfma_f32_16x16x32_bf16(
                    af[mi], bfv[ni], acc[mi][ni], 0, 0, 0);
    }

#pragma unroll
    for (int mi = 0; mi < 4; mi++) {
#pragma unroll
        for (int ni = 0; ni < 4; ni++) {
            const int gn = n0 + wc * 64 + ni * 16 + l16;
            const int gmb = m0 + wr * 64 + mi * 16 + quad * 4;
#pragma unroll
            for (int r = 0; r < 4; r++) {
                const int gm = gmb + r;
                float v = acc[mi][ni][r];
                if constexpr (MODE == 0) {
                    ((u16*)Cout)[(size_t)gm * N + gn] = f2bf(v + bias[gn]);
                } else if constexpr (MODE == 1) {
                    ((float*)Cout)[(size_t)gm * N + gn] = v;
                } else if constexpr (MODE == 2) {
                    float t = v + bias[gn];
                    float ge = 0.5f * t * (1.0f + erff(t * 0.70710678118f));
                    ((u16*)Cout)[(size_t)gm * N + gn] = f2bf(ge);
                } else {
                    ((float*)Cout)[(size_t)gm * N + gn] = v + bias[gn] + add[(size_t)gm * N + gn];
                }
            }
        }
    }
}

// ---------------------------------------------------------------- spectral prep
__global__ __launch_bounds__(512) void prep_freq_kernel(
    const float* __restrict__ fi, const float* __restrict__ logd,
    const float* __restrict__ freqs, const float* __restrict__ dt,
    float* __restrict__ rr, float* __restrict__ ri,
    float* __restrict__ Ar, float* __restrict__ Ai)
{
    __shared__ float red[512];
    int f = threadIdx.x;
    float v = fi[f];
    red[f] = v; __syncthreads();
    for (int s = 256; s > 0; s >>= 1) { if (f < s) red[f] = fmaxf(red[f], red[f + s]); __syncthreads(); }
    float mx = red[0]; __syncthreads();
    float e = expf(v - mx);
    red[f] = e; __syncthreads();
    for (int s = 256; s > 0; s >>= 1) { if (f < s) red[f] += red[f + s]; __syncthreads(); }
    float sm = e / red[0];
    float decay = sigm(logd[f]) * (sm * (float)NFf);
    float omega = freqs[f] * 0.1f * (sigm(dt[f]) * 2.0f);
    float cc = cosf(omega), ss = sinf(omega);
    rr[f] = cc; ri[f] = ss; Ar[f] = decay * cc; Ai[f] = decay * ss;
}

// u = (sp_re + i sp_im) * sigmoid(fg); also extract ts, bs
__global__ __launch_bounds__(256) void prepA_kernel(
    const u16* __restrict__ Z, float* __restrict__ u_re, float* __restrict__ u_im,
    float* __restrict__ ts, float* __restrict__ bs)
{
    int i = blockIdx.x * 256 + threadIdx.x;
    if (i >= Mm * NFf) return;
    int m = i >> 9, f = i & (NFf - 1);
    const u16* zr = Z + (size_t)m * NZz;
    float fg  = sigm(bf2f(zr[2048 + f]));
    float spr = bf2f(zr[3584 + f]);
    float spi = bf2f(zr[3584 + NFf + f]);
    u_re[i] = spr * fg;
    u_im[i] = spi * fg;
    if (f == 0) {
        ts[m] = sigm(bf2f(zr[4608]));
#pragma unroll
        for (int j = 0; j < NBb; j++) bs[m * NBb + j] = sigm(bf2f(zr[4609 + j]));
    }
}

// k[b,tau,f] = ts[b,tau] * rot[f] * prod_{s<tau} (A[f]*bs[b,s,band(f)])
__global__ __launch_bounds__(256) void makek_kernel(
    const float* __restrict__ Ar, const float* __restrict__ Ai,
    const float* __restrict__ rr, const float* __restrict__ ri,
    const float* __restrict__ ts, const float* __restrict__ bs,
    float* __restrict__ k_re, float* __restrict__ k_im)
{
    int g = blockIdx.x * 256 + threadIdx.x;
    if (g >= Bb * NFf) return;
    int b = g / NFf, f = g % NFf;
    float Pr = 1.0f, Pi = 0.0f;
    float ar = Ar[f], ai = Ai[f], cr = rr[f], ci = ri[f];
    int band = f / (NFf / NBb);
    for (int tau = 0; tau < Ll; tau++) {
        float tsv = ts[b * Tt + tau];
        k_re[(size_t)(b * Ll + tau) * NFf + f] = tsv * (cr * Pr - ci * Pi);
        k_im[(size_t)(b * Ll + tau) * NFf + f] = tsv * (cr * Pi + ci * Pr);
        float bsv = bs[(b * Tt + tau) * NBb + band];
        float er = ar * bsv, ei = ai * bsv;
        float nPr = Pr * er - Pi * ei;
        float nPi = Pr * ei + Pi * er;
        Pr = nPr; Pi = nPi;
    }
}

// y[b,t,f] = sum_{tau<64} u[b,t-tau,f]*k[b,tau,f]
// block: 64 f x 4 ty; each thread computes 4 consecutive t via sliding register window.
__global__ __launch_bounds__(256) void conv_kernel(
    const float* __restrict__ u_re, const float* __restrict__ u_im,
    const float* __restrict__ k_re, const float* __restrict__ k_im,
    u16* __restrict__ spec)
{
    __shared__ float skr[64 * 64], ski[64 * 64];   // [tau][f] 16 KB each
    const int fl = threadIdx.x;               // 0..63
    const int ty = threadIdx.y;               // 0..3
    const int f0 = blockIdx.x * 64;
    const int b  = blockIdx.z;
    const int t0 = (blockIdx.y * 4 + ty) * 4; // this thread: t0..t0+3

    const int tid = ty * 64 + fl;
    for (int i = tid; i < 64 * 64; i += 256) {
        int tau = i >> 6, ff = i & 63;
        size_t gi = (size_t)(b * Ll + tau) * NFf + f0 + ff;
        skr[i] = k_re[gi];
        ski[i] = k_im[gi];
    }
    __syncthreads();

    const int f = f0 + fl;
    const size_t ubase = (size_t)(b * Tt) * NFf + f;
    float wr[4], wi[4];   // wr[j] = u[t0+j-tau] (0 if t0+j-tau<0)
#pragma unroll
    for (int j = 0; j < 4; j++) {
        wr[j] = u_re[ubase + (size_t)(t0 + j) * NFf];
        wi[j] = u_im[ubase + (size_t)(t0 + j) * NFf];
    }
    float yr[4] = {0.f,0.f,0.f,0.f}, yi[4] = {0.f,0.f,0.f,0.f};
    for (int tau = 0; tau < Ll; tau++) {
        float kr = skr[tau * 64 + fl], ki = ski[tau * 64 + fl];
#pragma unroll
        for (int j = 0; j < 4; j++) {
            yr[j] += wr[j] * kr - wi[j] * ki;
            yi[j] += wr[j] * ki + wi[j] * kr;
        }
#pragma unroll
        for (int j = 3; j >= 1; j--) { wr[j] = wr[j-1]; wi[j] = wi[j-1]; }
        int trow = t0 - tau - 1;
        if (trow >= 0) {
            wr[0] = u_re[ubase + (size_t)trow * NFf];
            wi[0] = u_im[ubase + (size_t)trow * NFf];
        } else { wr[0] = 0.f; wi[0] = 0.f; }
    }
#pragma unroll
    for (int j = 0; j < 4; j++) {
        size_t row = (size_t)(b * Tt + t0 + j);
        spec[row * (2 * NFf) + f]       = f2bf(yr[j]);
        spec[row * (2 * NFf) + NFf + f] = f2bf(yi[j]);
    }
}

// x2 = x + 0.5*(P2*os*sigmoid(gate) + concept*sigmoid(cg)); xn2 = LN2(x2) bf16
__global__ __launch_bounds__(256) void fuse2_ln_kernel(
    const float* __restrict__ x, const u16* __restrict__ Z,
    const float* __restrict__ P2, const float* __restrict__ osc,
    const float* __restrict__ g2, const float* __restrict__ b2v,
    float* __restrict__ x2, u16* __restrict__ xn2)
{
    const int m = blockIdx.x, tid = threadIdx.x;
    const float os = osc[0];
    const u16* zr = Z + (size_t)m * NZz;
    float4 xv = ((const float4*)(x + (size_t)m * Dd))[tid];
    float4 pv = ((const float4*)(P2 + (size_t)m * Dd))[tid];
    float vals[4]; float s1 = 0.0f, s2 = 0.0f;
#pragma unroll
    for (int j = 0; j < 4; j++) {
        int d = tid * 4 + j;
        float concept = bf2f(zr[d]);
        float cg   = sigm(bf2f(zr[1024 + d]));
        float gate = sigm(bf2f(zr[2560 + d]));
        float p = (&pv.x)[j];
        float v = (&xv.x)[j] + 0.5f * (p * os * gate + concept * cg);
        vals[j] = v; s1 += v; s2 += v * v;
    }
    __shared__ float lds[16];
    for (int o = 32; o; o >>= 1) { s1 += __shfl_down(s1, o); s2 += __shfl_down(s2, o); }
    int lane = tid & 63, w = tid >> 6;
    if (!lane) { lds[w] = s1; lds[8 + w] = s2; }
    __syncthreads();
    s1 = lds[0] + lds[1] + lds[2] + lds[3];
    s2 = lds[8] + lds[9] + lds[10] + lds[11];
    float mean = s1 * (1.0f / Dd);
    float var  = s2 * (1.0f / Dd) - mean * mean;
    float rstd = rsqrtf(var + 1e-5f);
    float4 xo; ushort4 no;
#pragma unroll
    for (int j = 0; j < 4; j++) {
        int d = tid * 4 + j;
        (&xo.x)[j] = vals[j];
        (&no.x)[j] = f2bf((vals[j] - mean) * rstd * g2[d] + b2v[d]);
    }
    ((float4*)(x2 + (size_t)m * Dd))[tid] = xo;
    ((ushort4*)(xn2 + (size_t)m * Dd))[tid] = no;
}

// ---------------------------------------------------------------- launch
extern "C" void kernel_launch(void* const* d_in, const int* in_sizes, int n_in,
                              void* d_out, int out_size, void* d_ws, size_t ws_size,
                              hipStream_t stream)
{
    const float* x        = (const float*)d_in[0];
    const float* norm_g   = (const float*)d_in[1];
    const float* norm_b   = (const float*)d_in[2];
    const float* Wconcept = (const float*)d_in[3];
    const float* bconcept = (const float*)d_in[4];
    const float* Wcg      = (const float*)d_in[5];
    const float* bcg      = (const float*)d_in[6];
    const float* Wfg      = (const float*)d_in[7];
    const float* bfg      = (const float*)d_in[8];
    const float* Wtg      = (const float*)d_in[9];
    const float* btg      = (const float*)d_in[10];
    const float* Wband    = (const float*)d_in[11];
    const float* bband    = (const float*)d_in[12];
    const float* Wsp      = (const float*)d_in[13];
    const float* fi       = (const float*)d_in[14];
    const float* logd     = (const float*)d_in[15];
    const float* freqs    = (const float*)d_in[16];
    const float* dtv      = (const float*)d_in[17];
    const float* Wgate    = (const float*)d_in[18];
    const float* bgate    = (const float*)d_in[19];
    const float* Wfs      = (const float*)d_in[20];
    const float* osc      = (const float*)d_in[21];
    const float* n2g      = (const float*)d_in[22];
    const float* n2b      = (const float*)d_in[23];
    const float* W1       = (const float*)d_in[24];
    const float* b1       = (const float*)d_in[25];
    const float* W2       = (const float*)d_in[26];
    const float* b2       = (const float*)d_in[27];

    char* ws = (char*)d_ws;
    size_t off = 0;
    auto alloc = [&](size_t bytes) { size_t c = off; off += (bytes + 255) & ~(size_t)255; return c; };
    size_t o_wcat = alloc((size_t)NZz * Dd * 2);
    size_t o_bias = alloc((size_t)NZz * 4);
    size_t o_wfs  = alloc((size_t)Dd * 2 * NFf * 2);
    size_t o_w1   = alloc((size_t)4 * Dd * Dd * 2);
    size_t o_w2   = alloc((size_t)4 * Dd * Dd * 2);
    size_t o_xn   = alloc((size_t)Mm * Dd * 2);
    size_t o_Z    = alloc((size_t)Mm * NZz * 2);        // later reused for h (Mm*4096*2 fits)
    size_t o_u    = alloc((size_t)Mm * NFf * 4 * 2);    // u_re|u_im; later P2, then x2 (in place)
    size_t o_spec = alloc((size_t)Mm * Dd * 2);         // spectral; later xn2
    size_t o_kre  = alloc((size_t)Bb * Ll * NFf * 4);
    size_t o_kim  = alloc((size_t)Bb * Ll * NFf * 4);
    size_t o_rr   = alloc(NFf * 4);
    size_t o_ri   = alloc(NFf * 4);
    size_t o_Ar   = alloc(NFf * 4);
    size_t o_Ai   = alloc(NFf * 4);
    size_t o_ts   = alloc(Mm * 4);
    size_t o_bs   = alloc((size_t)Mm * NBb * 4);
    if (ws_size < off) return;

    u16*   wcat = (u16*)(ws + o_wcat);
    float* bias = (float*)(ws + o_bias);
    u16*   wfs  = (u16*)(ws + o_wfs);
    u16*   w1b  = (u16*)(ws + o_w1);
    u16*   w2b  = (u16*)(ws + o_w2);
    u16*   xn   = (u16*)(ws + o_xn);
    u16*   Zb   = (u16*)(ws + o_Z);
    u16*   hb   = (u16*)(ws + o_Z);
    float* u_re = (float*)(ws + o_u);
    float* u_im = (float*)(ws + o_u + (size_t)Mm * NFf * 4);
    float* P2   = (float*)(ws + o_u);
    float* x2   = (float*)(ws + o_u);     // in-place over P2 (same-thread read->write)
    u16*   spec = (u16*)(ws + o_spec);
    u16*   xn2  = (u16*)(ws + o_spec);
    float* kre  = (float*)(ws + o_kre);
    float* kim  = (float*)(ws + o_kim);
    float* rr   = (float*)(ws + o_rr);
    float* ri   = (float*)(ws + o_ri);
    float* Ar   = (float*)(ws + o_Ar);
    float* Ai   = (float*)(ws + o_Ai);
    float* ts   = (float*)(ws + o_ts);
    float* bs   = (float*)(ws + o_bs);

    // 1) weight packing / bf16 conversion
    wpack_kernel<<<(NZz * Dd + 255) / 256, 256, 0, stream>>>(
        Wconcept, Wcg, Wfg, Wgate, Wsp, Wtg, Wband,
        bconcept, bcg, bfg, bgate, btg, bband, wcat, bias);
    f2bf_kernel<<<(Dd * 2 * NFf + 255) / 256, 256, 0, stream>>>(Wfs, wfs, Dd * 2 * NFf);
    f2bf_kernel<<<(4 * Dd * Dd + 255) / 256, 256, 0, stream>>>(W1, w1b, 4 * Dd * Dd);
    f2bf_kernel<<<(4 * Dd * Dd + 255) / 256, 256, 0, stream>>>(W2, w2b, 4 * Dd * Dd);

    // 2) LN1 -> xn (bf16)
    ln_kernel<<<Mm, 256, 0, stream>>>(x, norm_g, norm_b, xn);

    // 3) fused projection GEMM: Z = xn @ wcat^T + bias  (8192 x 4736, K=1024)
    gemm_bt<0><<<dim3(Mm / 128, NZz / 128), 256, 0, stream>>>(
        xn, wcat, bias, nullptr, (void*)Zb, Mm, NZz, Dd);

    // 4) spectral constants, u, conv kernel coefficients
    prep_freq_kernel<<<1, 512, 0, stream>>>(fi, logd, freqs, dtv, rr, ri, Ar, Ai);
    prepA_kernel<<<(Mm * NFf + 255) / 256, 256, 0, stream>>>(Zb, u_re, u_im, ts, bs);
    makek_kernel<<<(Bb * NFf + 255) / 256, 256, 0, stream>>>(Ar, Ai, rr, ri, ts, bs, kre, kim);

    // 5) truncated causal convolution -> spectral_out (bf16)
    conv_kernel<<<dim3(NFf / 64, Tt / 16, Bb), dim3(64, 4), 0, stream>>>(u_re, u_im, kre, kim, spec);

    // 6) y_proj raw: P2 = spectral @ Wfs^T   (8192 x 1024, K=2048)
    gemm_bt<1><<<dim3(Mm / 128, Dd / 128), 256, 0, stream>>>(
        spec, wfs, nullptr, nullptr, (void*)P2, Mm, Dd, 2 * NFf);

    // 7) gate/concept fuse + residual + LN2
    fuse2_ln_kernel<<<Mm, 256, 0, stream>>>(x, Zb, P2, osc, n2g, n2b, x2, xn2);

    // 8) MLP
    gemm_bt<2><<<dim3(Mm / 128, (4 * Dd) / 128), 256, 0, stream>>>(
        xn2, w1b, b1, nullptr, (void*)hb, Mm, 4 * Dd, Dd);
    gemm_bt<3><<<dim3(Mm / 128, Dd / 128), 256, 0, stream>>>(
        hb, w2b, b2, x2, d_out, Mm, Dd, 4 * Dd);
}